// Round 7
// baseline (454.074 us; speedup 1.0000x reference)
//
#include <hip/hip_runtime.h>
#include <hip/hip_cooperative_groups.h>
#include <math.h>

namespace cg = cooperative_groups;

#define NN 65536
#define NE 1048576
#define KH 48
#define G3 144
#define GRID 256

#define CAP_L1 8192
#define CAP_S1 4096
#define CAP_E2 65536
#define CAP_S2 8192

// ws byte offsets
#define OFF_MARK1  0u        // NN i32
#define OFF_MARK2  262144u   // NN i32
#define OFF_CNT    524288u   // 16 u32: [0]=cntL1 [1]=cntS1 [2]=cntE2 [3]=cntS2
#define OFF_L1R    524352u   // CAP_L1 i32
#define OFF_L1W    557120u   // CAP_L1 f32
#define OFF_S1G    589888u   // CAP_S1 i32
#define OFF_E2R    606272u   // CAP_E2 i32
#define OFF_E2S    868416u   // CAP_E2 i32
#define OFF_E2W    1130560u  // CAP_E2 f32
#define OFF_S2     1392704u  // CAP_S2 i32
#define OFF_DEG2   1425472u  // CAP_S2 f32
#define OFF_STATE  1458240u  // CAP_S2*48 f32
#define OFF_X1     3031104u  // CAP_S1*48 f32
#define OFF_TPSF   3817536u  // 128 f32
#define OFF_CONC   3818048u  // 144 f32

typedef _Float16 h2_t __attribute__((ext_vector_type(2)));
struct __align__(16) h2x4 { h2_t a, b, c, d; };

__device__ __forceinline__ float sigmf(float x) { return 1.0f / (1.0f + expf(-x)); }

#if __has_builtin(__builtin_amdgcn_fdot2)
__device__ __forceinline__ float fdot2f(h2_t a, h2_t b, float c) {
    return __builtin_amdgcn_fdot2(a, b, c, false);
}
#else
__device__ __forceinline__ float fdot2f(h2_t a, h2_t b, float c) {
    return c + (float)a.x * (float)b.x + (float)a.y * (float)b.y;
}
#endif

// conv1d(pad=1,k=3) + GRU over one sequence (block-level; blockDim>=192)
__device__ void gru_seq(const float* xseq, int T,
                        const float* cw, const float* cb,
                        const float* Wih, const float* Whh,
                        const float* bih, const float* bhh,
                        float* out48,
                        float* s_x, float* s_embed, float* s_giA,
                        float* s_h, float* s_gh) {
    int t = threadIdx.x;
    int nt = blockDim.x;
    for (int i = t; i < T * 2; i += nt) s_x[i] = xseq[i];
    __syncthreads();
    for (int idx = t; idx < T * KH; idx += nt) {
        int tt = idx / KH;
        int k = idx - tt * KH;
        float acc = cb[k];
#pragma unroll
        for (int d = 0; d < 3; ++d) {
            int tau = tt + d - 1;
            if (tau >= 0 && tau < T) {
                acc += cw[k * 6 + d] * s_x[tau * 2 + 0];
                acc += cw[k * 6 + 3 + d] * s_x[tau * 2 + 1];
            }
        }
        s_embed[tt * KH + k] = fmaxf(acc, 0.0f);
    }
    __syncthreads();
    // gi = Wih@embed + bih for all steps (parallel; not recurrent)
    for (int idx = t; idx < T * G3; idx += nt) {
        int step = idx / G3;
        int row = idx - step * G3;
        const float4* wp = reinterpret_cast<const float4*>(Wih + row * KH);
        const float4* em = reinterpret_cast<const float4*>(s_embed + step * KH);
        float g = bih[row];
#pragma unroll
        for (int j = 0; j < 12; ++j) {
            float4 w4 = wp[j]; float4 e4 = em[j];
            g += w4.x * e4.x + w4.y * e4.y + w4.z * e4.z + w4.w * e4.w;
        }
        s_giA[idx] = g;
    }
    float4 wh[12];
    float bh = 0.0f;
    if (t < G3) {
        const float4* q = reinterpret_cast<const float4*>(Whh + t * KH);
#pragma unroll
        for (int j = 0; j < 12; ++j) wh[j] = q[j];
        bh = bhh[t];
    }
    if (t < KH) s_h[t] = 0.0f;
    __syncthreads();
    for (int step = 0; step < T; ++step) {
        if (t < G3) {
            const float4* hp = reinterpret_cast<const float4*>(s_h);
            float g = bh;
#pragma unroll
            for (int j = 0; j < 12; ++j) {
                float4 h4 = hp[j];
                g += wh[j].x * h4.x + wh[j].y * h4.y + wh[j].z * h4.z + wh[j].w * h4.w;
            }
            s_gh[t] = g;
        }
        __syncthreads();
        if (t < KH) {
            const float* gi = s_giA + step * G3;
            float r = sigmf(gi[t] + s_gh[t]);
            float z = sigmf(gi[KH + t] + s_gh[KH + t]);
            float n = tanhf(gi[2 * KH + t] + r * s_gh[2 * KH + t]);
            s_h[t] = (1.0f - z) * n + z * s_h[t];
        }
        __syncthreads();
    }
    if (t < KH) out48[t] = s_h[t];
}

// ============ Launch A: graph prep + GRUs + GCN, R4-proven config ==========
__global__ __launch_bounds__(256, 2) void k_all(
    const float* past, const float* future, const float* x,
    const int* ei, const float* ew,
    const float* cpw, const float* cpb, const float* cfw, const float* cfb,
    const float* epWih, const float* epWhh, const float* epbih, const float* epbhh,
    const float* efWih, const float* efWhh, const float* efbih, const float* efbhh,
    const float* g1w, const float* g1b, const float* g2w, const float* g2b,
    int* mark1, int* mark2, unsigned* cnt,
    int* l1r, float* l1w, int* s1g,
    int* e2r, int* e2s, float* e2w,
    int* s2, float* deg2, float* state, float* x1, float* tpsf,
    float* conc_g) {
    __shared__ __align__(16) float s_x[80];
    __shared__ __align__(16) float s_embed[40 * KH];
    __shared__ __align__(16) float s_giA[40 * G3];
    __shared__ __align__(16) float s_hG[KH];
    __shared__ float s_ghG[G3];
    __shared__ __align__(16) float s_conc[G3];

    cg::grid_group grid = cg::this_grid();
    int tid = blockIdx.x * blockDim.x + threadIdx.x;
    int nth = gridDim.x * blockDim.x;

    // ---- P0: init ----
    for (int i = tid; i < NN; i += nth) { mark1[i] = (i == 0) ? 1 : 0; mark2[i] = 0; }
    if (tid < 16) cnt[tid] = 0;
    grid.sync();

    // ---- P1: edges into node 0 ----
    for (int q = tid; q < NE / 4; q += nth) {
        int4 c4 = reinterpret_cast<const int4*>(ei + NE)[q];
        int e = q * 4;
        int cc[4] = {c4.x, c4.y, c4.z, c4.w};
#pragma unroll
        for (int j = 0; j < 4; ++j) {
            if (cc[j] == 0) {
                int r = ei[e + j];
                float w = ew[e + j];
                unsigned s = atomicAdd(&cnt[0], 1u);
                if (s < CAP_L1) { l1r[s] = r; l1w[s] = w; }
                mark1[r] = 1;
            }
        }
    }
    grid.sync();

    // ---- P2: compact S1; self-loop E2 entries; x1 bias init ----
    for (int i = tid; i < NN; i += nth) {
        if (mark1[i]) {
            unsigned s = atomicAdd(&cnt[1], 1u);
            if (s < CAP_S1) {
                mark1[i] = (int)s + 1;
                mark2[i] = 1;
                s1g[s] = i;
                unsigned t2 = atomicAdd(&cnt[2], 1u);
                if (t2 < CAP_E2) { e2r[t2] = i; e2s[t2] = (int)s; e2w[t2] = 1.0f; }
                for (int k = 0; k < KH; ++k) x1[s * KH + k] = g1b[k];
            } else mark1[i] = 0;
        }
    }
    grid.sync();

    // ---- P3: collect edges into S1 ----
    for (int q = tid; q < NE / 4; q += nth) {
        int4 c4 = reinterpret_cast<const int4*>(ei + NE)[q];
        int e = q * 4;
        int cc[4] = {c4.x, c4.y, c4.z, c4.w};
#pragma unroll
        for (int j = 0; j < 4; ++j) {
            int m = mark1[cc[j]];
            if (m > 0) {
                int r = ei[e + j];
                float w = ew[e + j];
                unsigned s = atomicAdd(&cnt[2], 1u);
                if (s < CAP_E2) { e2r[s] = r; e2s[s] = m - 1; e2w[s] = w; }
                mark2[r] = 1;
            }
        }
    }
    grid.sync();

    // ---- P4: compact S2; init degree ----
    for (int i = tid; i < NN; i += nth) {
        if (mark2[i]) {
            unsigned s = atomicAdd(&cnt[3], 1u);
            if (s < CAP_S2) { s2[s] = i; mark2[i] = (int)s + 1; deg2[s] = 1.0f; }
            else mark2[i] = 0;
        }
    }
    grid.sync();

    // ---- P5: degree scan (S2 only) + all GRUs ----
    for (int e = tid; e < NE; e += nth) {
        int c = ei[NE + e];
        int m = mark2[c];
        if (m > 0) atomicAdd(&deg2[m - 1], ew[e]);
    }
    int cnt2 = (int)min(cnt[3], (unsigned)CAP_S2);
    for (int it = blockIdx.x; it < cnt2 + 2; it += gridDim.x) {
        if (it < cnt2) {
            gru_seq(x + (size_t)s2[it] * 40, 20, cpw, cpb, epWih, epWhh, epbih, epbhh,
                    state + (size_t)it * KH, s_x, s_embed, s_giA, s_hG, s_ghG);
        } else if (it == cnt2) {
            gru_seq(past, 20, cpw, cpb, epWih, epWhh, epbih, epbhh,
                    tpsf, s_x, s_embed, s_giA, s_hG, s_ghG);
        } else {
            gru_seq(future, 40, cfw, cfb, efWih, efWhh, efbih, efbhh,
                    tpsf + 64, s_x, s_embed, s_giA, s_hG, s_ghG);
        }
    }
    grid.sync();

    // ---- P6: GCN layer 1 edge accumulation ----
    int nE = (int)min(cnt[2], (unsigned)CAP_E2);
    for (int idx = tid; idx < nE * KH; idx += nth) {
        int e = idx / KH;
        int k = idx - e * KH;
        int row = e2r[e];
        int s2i = mark2[row] - 1;
        if (s2i < 0) continue;
        int cglob = s1g[e2s[e]];
        int cs2 = mark2[cglob] - 1;
        float norm = e2w[e] * rsqrtf(deg2[s2i] * deg2[cs2]);
        const float* sp = state + (size_t)s2i * KH;
        const float* wp = g1w + k * KH;
        float acc = 0.0f;
#pragma unroll
        for (int m = 0; m < KH; ++m) acc += sp[m] * wp[m];
        atomicAdd(&x1[e2s[e] * KH + k], acc * norm);
    }
    grid.sync();

    // ---- P7a: GCN layer 2 @ node 0 -> conc to global (block 0) ----
    if (blockIdx.x != 0) return;
    int t = threadIdx.x;
    if (t < 48) s_conc[t] = g2b[t];
    else if (t < 96) s_conc[t] = tpsf[t - 48];
    else if (t < 144) s_conc[t] = tpsf[64 + t - 96];
    __syncthreads();
    int cl1 = (int)min(cnt[0], (unsigned)CAP_L1);
    float dinv0 = rsqrtf(deg2[mark2[0] - 1]);
    int items = (cl1 + 1) * KH;
    for (int idx = t; idx < items; idx += 256) {
        int e = idx / KH;
        int k = idx - e * KH;
        int row; float norm;
        if (e == cl1) { row = 0; norm = dinv0 * dinv0; }
        else {
            row = l1r[e];
            int rs2 = mark2[row] - 1;
            if (rs2 < 0) continue;
            norm = l1w[e] * rsqrtf(deg2[rs2]) * dinv0;
        }
        int s1 = mark1[row] - 1;
        if (s1 < 0) continue;
        const float* xp = x1 + (size_t)s1 * KH;
        const float* wp = g2w + k * KH;
        float acc = 0.0f;
#pragma unroll
        for (int m = 0; m < KH; ++m) acc += fmaxf(xp[m], 0.0f) * wp[m];
        atomicAdd(&s_conc[k], acc * norm);
    }
    __syncthreads();
    if (t < G3) conc_g[t] = s_conc[t];
}

// ============ Launch B: 40-step decoder (plain launch, 1 block) ============
// One full dWhh row per thread as f16 (18 h2x4 = 72 VGPRs); h re-read per
// step as 18 ds_read_b128. 432 active threads of 448.
__global__ __launch_bounds__(448, 2) void k_dec2(
    const float* conc_g, const float* past,
    const float* dWih, const float* dWhh, const float* dbih, const float* dbhh,
    const float* fcw, const float* fcb, float* out) {
    __shared__ __align__(16) float s_conc[G3];
    __shared__ __align__(16) float s_hD[G3];
    __shared__ __align__(16) _Float16 s_h16[G3];
    __shared__ float s_gi0[3 * G3], s_gh[3 * G3], s_bih[3 * G3];
    int t = threadIdx.x;
    if (t < G3) s_conc[t] = conc_g[t];
    for (int i = t; i < 3 * G3; i += 448) s_bih[i] = dbih[i];
    if (t < G3) { s_hD[t] = 0.0f; s_h16[t] = (_Float16)0.0f; }
    // weights: row t of dWhh, f16
    h2x4 wr[18];
    float bh = 0.0f;
    if (t < 3 * G3) {
        const float4* q = reinterpret_cast<const float4*>(dWhh + t * G3);
#pragma unroll
        for (int j = 0; j < 18; ++j) {
            float4 a = q[2 * j], b = q[2 * j + 1];
            wr[j].a = h2_t{(_Float16)a.x, (_Float16)a.y};
            wr[j].b = h2_t{(_Float16)a.z, (_Float16)a.w};
            wr[j].c = h2_t{(_Float16)b.x, (_Float16)b.y};
            wr[j].d = h2_t{(_Float16)b.z, (_Float16)b.w};
        }
        bh = dbhh[t];
    }
    float pres = 0.0f;
    if (t == 0 || t == 64) pres = past[38 + (t >> 6)];
    __syncthreads();   // s_conc ready
    // gi at step 0 (steps >=1: input zeros -> gi = bih)
    if (t < 3 * G3) {
        const float4* p = reinterpret_cast<const float4*>(dWih + t * G3);
        const float4* cc = reinterpret_cast<const float4*>(s_conc);
        float g = 0.0f;
#pragma unroll
        for (int j = 0; j < 36; ++j) {
            float4 w4 = p[j]; float4 c4 = cc[j];
            g += w4.x * c4.x + w4.y * c4.y + w4.z * c4.z + w4.w * c4.w;
        }
        s_gi0[t] = g + s_bih[t];
    }
    for (int i = 0; i < 40; ++i) {
        if (t < 3 * G3) {
            const h2x4* hp = reinterpret_cast<const h2x4*>(s_h16);
            float g = 0.0f;
#pragma unroll
            for (int j = 0; j < 18; ++j) {
                h2x4 h = hp[j];
                g = fdot2f(wr[j].a, h.a, g);
                g = fdot2f(wr[j].b, h.b, g);
                g = fdot2f(wr[j].c, h.c, g);
                g = fdot2f(wr[j].d, h.d, g);
            }
            s_gh[t] = g + bh;
        }
        __syncthreads();
        if (t < G3) {
            float gr = (i == 0) ? s_gi0[t] : s_bih[t];
            float gz = (i == 0) ? s_gi0[G3 + t] : s_bih[G3 + t];
            float gn = (i == 0) ? s_gi0[2 * G3 + t] : s_bih[2 * G3 + t];
            float r = sigmf(gr + s_gh[t]);
            float z = sigmf(gz + s_gh[G3 + t]);
            float n = tanhf(gn + r * s_gh[2 * G3 + t]);
            float hnew = (1.0f - z) * n + z * s_hD[t];
            s_hD[t] = hnew;
            s_h16[t] = (_Float16)hnew;
        }
        __syncthreads();
        int w = t >> 6;
        if (w < 2) {
            int lane = t & 63;
            float pp = 0.0f;
            for (int m = lane; m < G3; m += 64) pp += s_hD[m] * fcw[w * G3 + m];
#pragma unroll
            for (int off = 32; off > 0; off >>= 1) pp += __shfl_down(pp, off);
            if (lane == 0) {
                pres += pp + fcb[w];
                out[i * 2 + w] = pres;
            }
        }
    }
}

extern "C" void kernel_launch(void* const* d_in, const int* in_sizes, int n_in,
                              void* d_out, int out_size, void* d_ws, size_t ws_size,
                              hipStream_t stream) {
    (void)in_sizes; (void)n_in; (void)out_size; (void)ws_size;
    const float* past   = (const float*)d_in[0];
    const float* future = (const float*)d_in[1];
    const float* x      = (const float*)d_in[2];
    const int*   ei     = (const int*)d_in[3];
    const float* ew     = (const float*)d_in[4];
    const float* cpw    = (const float*)d_in[5];
    const float* cpb    = (const float*)d_in[6];
    const float* cfw    = (const float*)d_in[7];
    const float* cfb    = (const float*)d_in[8];
    const float* epWih  = (const float*)d_in[9];
    const float* epWhh  = (const float*)d_in[10];
    const float* epbih  = (const float*)d_in[11];
    const float* epbhh  = (const float*)d_in[12];
    const float* efWih  = (const float*)d_in[13];
    const float* efWhh  = (const float*)d_in[14];
    const float* efbih  = (const float*)d_in[15];
    const float* efbhh  = (const float*)d_in[16];
    const float* dWih   = (const float*)d_in[17];
    const float* dWhh   = (const float*)d_in[18];
    const float* dbih   = (const float*)d_in[19];
    const float* dbhh   = (const float*)d_in[20];
    const float* fcw    = (const float*)d_in[21];
    const float* fcb    = (const float*)d_in[22];
    const float* g1w    = (const float*)d_in[23];
    const float* g1b    = (const float*)d_in[24];
    const float* g2w    = (const float*)d_in[25];
    const float* g2b    = (const float*)d_in[26];

    char* ws = (char*)d_ws;
    int*      mark1 = (int*)(ws + OFF_MARK1);
    int*      mark2 = (int*)(ws + OFF_MARK2);
    unsigned* cnt   = (unsigned*)(ws + OFF_CNT);
    int*      l1r   = (int*)(ws + OFF_L1R);
    float*    l1w   = (float*)(ws + OFF_L1W);
    int*      s1g   = (int*)(ws + OFF_S1G);
    int*      e2r   = (int*)(ws + OFF_E2R);
    int*      e2s   = (int*)(ws + OFF_E2S);
    float*    e2w   = (float*)(ws + OFF_E2W);
    int*      s2    = (int*)(ws + OFF_S2);
    float*    deg2  = (float*)(ws + OFF_DEG2);
    float*    state = (float*)(ws + OFF_STATE);
    float*    x1    = (float*)(ws + OFF_X1);
    float*    tpsf  = (float*)(ws + OFF_TPSF);
    float*    conc  = (float*)(ws + OFF_CONC);
    float*    out   = (float*)d_out;

    void* args[] = {
        &past, &future, &x, &ei, &ew,
        &cpw, &cpb, &cfw, &cfb,
        &epWih, &epWhh, &epbih, &epbhh,
        &efWih, &efWhh, &efbih, &efbhh,
        &g1w, &g1b, &g2w, &g2b,
        &mark1, &mark2, &cnt,
        &l1r, &l1w, &s1g,
        &e2r, &e2s, &e2w,
        &s2, &deg2, &state, &x1, &tpsf,
        &conc
    };
    hipLaunchCooperativeKernel((void*)k_all, dim3(GRID), dim3(256), args, 0, stream);
    k_dec2<<<1, 448, 0, stream>>>(conc, past, dWih, dWhh, dbih, dbhh, fcw, fcb, out);
}

// Round 8
// 301.424 us; speedup vs baseline: 1.5064x; 1.5064x over previous
//
#include <hip/hip_runtime.h>
#include <math.h>

#define NN 65536
#define NE 1048576
#define KH 48
#define G3 144
#define GRID 256

#define CAP_L1 8192
#define CAP_S1 4096
#define CAP_E2 65536
#define CAP_S2 8192

// ws byte offsets. [0, 524608) zeroed by one hipMemsetAsync per call.
#define OFF_MARK1  0u        // NN i32   (0 free, -1 claimed, s+1 = S1 slot)
#define OFF_MARK2  262144u   // NN i32   (0 free, -1 claimed, s+1 = S2 slot)
#define OFF_CNT    524288u   // 16 u32: [0]=cntL1 [1]=cntS1 [2]=cntE2 [3]=cntS2
#define OFF_BAR    524352u   // 3 barrier counters, 64B apart
#define OFF_L1R    524608u   // CAP_L1 i32
#define OFF_L1W    557376u   // CAP_L1 f32
#define OFF_S1G    590144u   // CAP_S1 i32 (S1 slot -> node id)
#define OFF_E2R    606528u   // CAP_E2 i32
#define OFF_E2S    868672u   // CAP_E2 i32
#define OFF_E2W    1130816u  // CAP_E2 f32
#define OFF_S2     1392960u  // CAP_S2 i32
#define OFF_DEG2   1425728u  // CAP_S2 f32
#define OFF_STATE  1458496u  // CAP_S2*48 f32
#define OFF_X1     3031360u  // CAP_S1*48 f32
#define OFF_TPSF   3817792u  // 128 f32

typedef _Float16 h2_t __attribute__((ext_vector_type(2)));
struct __align__(16) h2x4 { h2_t a, b, c, d; };

__device__ __forceinline__ float sigmf(float x) { return 1.0f / (1.0f + expf(-x)); }

#if __has_builtin(__builtin_amdgcn_fdot2)
__device__ __forceinline__ float fdot2f(h2_t a, h2_t b, float c) {
    return __builtin_amdgcn_fdot2(a, b, c, false);
}
#else
__device__ __forceinline__ float fdot2f(h2_t a, h2_t b, float c) {
    return c + (float)a.x * (float)b.x + (float)a.y * (float)b.y;
}
#endif

// Manual grid barrier: fence + device-scope arrive + poll. Safe: 256 blocks
// of 256 thr @ <=32KB LDS, launch_bounds(256,2) -> capacity 2 blocks/CU.
__device__ __forceinline__ void gbar(unsigned* ctr) {
    __syncthreads();
    if (threadIdx.x == 0) {
        __threadfence();
        __hip_atomic_fetch_add(ctr, 1u, __ATOMIC_ACQ_REL, __HIP_MEMORY_SCOPE_AGENT);
        while (__hip_atomic_load(ctr, __ATOMIC_RELAXED, __HIP_MEMORY_SCOPE_AGENT)
               < (unsigned)gridDim.x) {
            __builtin_amdgcn_s_sleep(1);
        }
        __threadfence();
    }
    __syncthreads();
}

__device__ __forceinline__ void allocS2(int r, int* mark2, unsigned* cnt,
                                        int* s2, float* deg2) {
    if (atomicCAS(&mark2[r], 0, -1) == 0) {
        int s = (int)atomicAdd(&cnt[3], 1u);
        if (s < CAP_S2) {
            s2[s] = r; deg2[s] = 1.0f;
            __threadfence();
            mark2[r] = s + 1;
        } else mark2[r] = 0;
    }
}

__device__ __forceinline__ void allocS1(int r, int* mark1, int* mark2,
                                        unsigned* cnt, int* s1g,
                                        int* e2r, int* e2s, float* e2w,
                                        int* s2, float* deg2,
                                        float* x1, const float* g1b) {
    if (atomicCAS(&mark1[r], 0, -1) == 0) {
        int s = (int)atomicAdd(&cnt[1], 1u);
        if (s < CAP_S1) {
            s1g[s] = r;
            unsigned t2 = atomicAdd(&cnt[2], 1u);  // self-loop E2 entry
            if (t2 < CAP_E2) { e2r[t2] = r; e2s[t2] = s; e2w[t2] = 1.0f; }
            for (int k = 0; k < KH; ++k) x1[s * KH + k] = g1b[k];
            allocS2(r, mark2, cnt, s2, deg2);
            __threadfence();
            mark1[r] = s + 1;
        } else mark1[r] = 0;
    }
}

// conv1d(pad=1,k=3) + GRU over one sequence (block-level, blockDim=256)
__device__ void gru_seq(const float* xseq, int T,
                        const float* cw, const float* cb,
                        const float* Wih, const float* Whh,
                        const float* bih, const float* bhh,
                        float* out48,
                        float* s_x, float* s_embed, float* s_giA,
                        float* s_h, float* s_gh) {
    int t = threadIdx.x;
    int nt = blockDim.x;
    for (int i = t; i < T * 2; i += nt) s_x[i] = xseq[i];
    __syncthreads();
    for (int idx = t; idx < T * KH; idx += nt) {
        int tt = idx / KH;
        int k = idx - tt * KH;
        float acc = cb[k];
#pragma unroll
        for (int d = 0; d < 3; ++d) {
            int tau = tt + d - 1;
            if (tau >= 0 && tau < T) {
                acc += cw[k * 6 + d] * s_x[tau * 2 + 0];
                acc += cw[k * 6 + 3 + d] * s_x[tau * 2 + 1];
            }
        }
        s_embed[tt * KH + k] = fmaxf(acc, 0.0f);
    }
    __syncthreads();
    // gi = Wih@embed + bih for all steps (parallel; not recurrent)
    for (int idx = t; idx < T * G3; idx += nt) {
        int step = idx / G3;
        int row = idx - step * G3;
        const float4* wp = reinterpret_cast<const float4*>(Wih + row * KH);
        const float4* em = reinterpret_cast<const float4*>(s_embed + step * KH);
        float g = bih[row];
#pragma unroll
        for (int j = 0; j < 12; ++j) {
            float4 w4 = wp[j]; float4 e4 = em[j];
            g += w4.x * e4.x + w4.y * e4.y + w4.z * e4.z + w4.w * e4.w;
        }
        s_giA[idx] = g;
    }
    float4 wh[12];
    float bh = 0.0f;
    if (t < G3) {
        const float4* q = reinterpret_cast<const float4*>(Whh + t * KH);
#pragma unroll
        for (int j = 0; j < 12; ++j) wh[j] = q[j];
        bh = bhh[t];
    }
    if (t < KH) s_h[t] = 0.0f;
    __syncthreads();
    for (int step = 0; step < T; ++step) {
        if (t < G3) {
            const float4* hp = reinterpret_cast<const float4*>(s_h);
            float g = bh;
#pragma unroll
            for (int j = 0; j < 12; ++j) {
                float4 h4 = hp[j];
                g += wh[j].x * h4.x + wh[j].y * h4.y + wh[j].z * h4.z + wh[j].w * h4.w;
            }
            s_gh[t] = g;
        }
        __syncthreads();
        if (t < KH) {
            const float* gi = s_giA + step * G3;
            float r = sigmf(gi[t] + s_gh[t]);
            float z = sigmf(gi[KH + t] + s_gh[KH + t]);
            float n = tanhf(gi[2 * KH + t] + r * s_gh[2 * KH + t]);
            s_h[t] = (1.0f - z) * n + z * s_h[t];
        }
        __syncthreads();
    }
    if (t < KH) out48[t] = s_h[t];
}

// ====== Kernel A: edge scans + CAS-alloc + deg + GRUs + GCN L1 =============
__global__ __launch_bounds__(256, 2) void k_main(
    const float* past, const float* future, const float* x,
    const int* ei, const float* ew,
    const float* cpw, const float* cpb, const float* cfw, const float* cfb,
    const float* epWih, const float* epWhh, const float* epbih, const float* epbhh,
    const float* efWih, const float* efWhh, const float* efbih, const float* efbhh,
    const float* g1w, const float* g1b,
    int* mark1, int* mark2, unsigned* cnt, unsigned* bar,
    int* l1r, float* l1w, int* s1g,
    int* e2r, int* e2s, float* e2w,
    int* s2, float* deg2, float* state, float* x1, float* tpsf) {
    __shared__ __align__(16) float s_x[80];
    __shared__ __align__(16) float s_embed[40 * KH];
    __shared__ __align__(16) float s_giA[40 * G3];
    __shared__ __align__(16) float s_hG[KH];
    __shared__ float s_ghG[G3];

    int tid = blockIdx.x * blockDim.x + threadIdx.x;
    int nth = gridDim.x * blockDim.x;

    // ---- P1: edges into node 0; S1 alloc at first touch ----
    if (tid == 0)
        allocS1(0, mark1, mark2, cnt, s1g, e2r, e2s, e2w, s2, deg2, x1, g1b);
    for (int q = tid; q < NE / 4; q += nth) {
        int4 c4 = reinterpret_cast<const int4*>(ei + NE)[q];
        int e = q * 4;
        int cc[4] = {c4.x, c4.y, c4.z, c4.w};
#pragma unroll
        for (int j = 0; j < 4; ++j) {
            if (cc[j] == 0) {
                int r = ei[e + j];
                float w = ew[e + j];
                unsigned s = atomicAdd(&cnt[0], 1u);
                if (s < CAP_L1) { l1r[s] = r; l1w[s] = w; }
                allocS1(r, mark1, mark2, cnt, s1g, e2r, e2s, e2w, s2, deg2, x1, g1b);
            }
        }
    }
    gbar(bar + 0);

    // ---- P3: edges into S1 -> E2; S2 alloc at first touch ----
    for (int q = tid; q < NE / 4; q += nth) {
        int4 c4 = reinterpret_cast<const int4*>(ei + NE)[q];
        int e = q * 4;
        int cc[4] = {c4.x, c4.y, c4.z, c4.w};
#pragma unroll
        for (int j = 0; j < 4; ++j) {
            int m = mark1[cc[j]];
            if (m > 0) {
                int r = ei[e + j];
                float w = ew[e + j];
                unsigned s = atomicAdd(&cnt[2], 1u);
                if (s < CAP_E2) { e2r[s] = r; e2s[s] = m - 1; e2w[s] = w; }
                allocS2(r, mark2, cnt, s2, deg2);
            }
        }
    }
    gbar(bar + 16);

    // ---- P5: degree scan (S2 only) + all GRUs ----
    for (int e = tid; e < NE; e += nth) {
        int c = ei[NE + e];
        int m = mark2[c];
        if (m > 0) atomicAdd(&deg2[m - 1], ew[e]);
    }
    int cnt2 = (int)min(cnt[3], (unsigned)CAP_S2);
    for (int it = blockIdx.x; it < cnt2 + 2; it += gridDim.x) {
        if (it < cnt2) {
            gru_seq(x + (size_t)s2[it] * 40, 20, cpw, cpb, epWih, epWhh, epbih, epbhh,
                    state + (size_t)it * KH, s_x, s_embed, s_giA, s_hG, s_ghG);
        } else if (it == cnt2) {
            gru_seq(past, 20, cpw, cpb, epWih, epWhh, epbih, epbhh,
                    tpsf, s_x, s_embed, s_giA, s_hG, s_ghG);
        } else {
            gru_seq(future, 40, cfw, cfb, efWih, efWhh, efbih, efbhh,
                    tpsf + 64, s_x, s_embed, s_giA, s_hG, s_ghG);
        }
    }
    gbar(bar + 32);

    // ---- P6: GCN layer 1 edge accumulation into x1 ----
    int nE = (int)min(cnt[2], (unsigned)CAP_E2);
    for (int idx = tid; idx < nE * KH; idx += nth) {
        int e = idx / KH;
        int k = idx - e * KH;
        int row = e2r[e];
        int s2i = mark2[row] - 1;
        if (s2i < 0) continue;
        int cglob = s1g[e2s[e]];
        int cs2 = mark2[cglob] - 1;
        float norm = e2w[e] * rsqrtf(deg2[s2i] * deg2[cs2]);
        const float* sp = state + (size_t)s2i * KH;
        const float* wp = g1w + k * KH;
        float acc = 0.0f;
#pragma unroll
        for (int m = 0; m < KH; ++m) acc += sp[m] * wp[m];
        atomicAdd(&x1[e2s[e] * KH + k], acc * norm);
    }
}

// ====== Kernel B: GCN layer 2 @ node 0 + 40-step decoder (1 block) =========
__global__ __launch_bounds__(448, 2) void k_dec2(
    const unsigned* cnt, const int* l1r, const float* l1w,
    const int* mark1, const int* mark2, const float* deg2, const float* x1,
    const float* g2w, const float* g2b, const float* tpsf, const float* past,
    const float* dWih, const float* dWhh, const float* dbih, const float* dbhh,
    const float* fcw, const float* fcb, float* out) {
    __shared__ __align__(16) float s_conc[G3];
    __shared__ __align__(16) float s_hD[G3];
    __shared__ __align__(16) _Float16 s_h16[G3];
    __shared__ float s_gi0[3 * G3], s_gh[3 * G3], s_bih[3 * G3];
    int t = threadIdx.x;
    if (t < 48) s_conc[t] = g2b[t];
    else if (t < 96) s_conc[t] = tpsf[t - 48];
    else if (t < 144) s_conc[t] = tpsf[64 + t - 96];
    for (int i = t; i < 3 * G3; i += 448) s_bih[i] = dbih[i];
    if (t < G3) { s_hD[t] = 0.0f; s_h16[t] = (_Float16)0.0f; }
    __syncthreads();
    // layer-2 message accumulation into s_conc[0..47]
    int cl1 = (int)min(cnt[0], (unsigned)CAP_L1);
    float dinv0 = rsqrtf(deg2[mark2[0] - 1]);
    int items = (cl1 + 1) * KH;
    for (int idx = t; idx < items; idx += 448) {
        int e = idx / KH;
        int k = idx - e * KH;
        int row; float norm;
        if (e == cl1) { row = 0; norm = dinv0 * dinv0; }
        else {
            row = l1r[e];
            int rs2 = mark2[row] - 1;
            if (rs2 < 0) continue;
            norm = l1w[e] * rsqrtf(deg2[rs2]) * dinv0;
        }
        int s1 = mark1[row] - 1;
        if (s1 < 0) continue;
        const float* xp = x1 + (size_t)s1 * KH;
        const float* wp = g2w + k * KH;
        float acc = 0.0f;
#pragma unroll
        for (int m = 0; m < KH; ++m) acc += fmaxf(xp[m], 0.0f) * wp[m];
        atomicAdd(&s_conc[k], acc * norm);
    }
    // decoder: one full dWhh row per thread as f16 (18 h2x4 = 72 VGPRs)
    h2x4 wr[18];
    float bh = 0.0f;
    if (t < 3 * G3) {
        const float4* q = reinterpret_cast<const float4*>(dWhh + t * G3);
#pragma unroll
        for (int j = 0; j < 18; ++j) {
            float4 a = q[2 * j], b = q[2 * j + 1];
            wr[j].a = h2_t{(_Float16)a.x, (_Float16)a.y};
            wr[j].b = h2_t{(_Float16)a.z, (_Float16)a.w};
            wr[j].c = h2_t{(_Float16)b.x, (_Float16)b.y};
            wr[j].d = h2_t{(_Float16)b.z, (_Float16)b.w};
        }
        bh = dbhh[t];
    }
    float pres = 0.0f;
    if (t == 0 || t == 64) pres = past[38 + (t >> 6)];
    __syncthreads();   // s_conc complete
    // gi at step 0 (steps >=1: input zeros -> gi = bih)
    if (t < 3 * G3) {
        const float4* p = reinterpret_cast<const float4*>(dWih + t * G3);
        const float4* cc = reinterpret_cast<const float4*>(s_conc);
        float g = 0.0f;
#pragma unroll
        for (int j = 0; j < 36; ++j) {
            float4 w4 = p[j]; float4 c4 = cc[j];
            g += w4.x * c4.x + w4.y * c4.y + w4.z * c4.z + w4.w * c4.w;
        }
        s_gi0[t] = g + s_bih[t];
    }
    for (int i = 0; i < 40; ++i) {
        if (t < 3 * G3) {
            const h2x4* hp = reinterpret_cast<const h2x4*>(s_h16);
            float g = 0.0f;
#pragma unroll
            for (int j = 0; j < 18; ++j) {
                h2x4 h = hp[j];
                g = fdot2f(wr[j].a, h.a, g);
                g = fdot2f(wr[j].b, h.b, g);
                g = fdot2f(wr[j].c, h.c, g);
                g = fdot2f(wr[j].d, h.d, g);
            }
            s_gh[t] = g + bh;
        }
        __syncthreads();
        if (t < G3) {
            float gr = (i == 0) ? s_gi0[t] : s_bih[t];
            float gz = (i == 0) ? s_gi0[G3 + t] : s_bih[G3 + t];
            float gn = (i == 0) ? s_gi0[2 * G3 + t] : s_bih[2 * G3 + t];
            float r = sigmf(gr + s_gh[t]);
            float z = sigmf(gz + s_gh[G3 + t]);
            float n = tanhf(gn + r * s_gh[2 * G3 + t]);
            float hnew = (1.0f - z) * n + z * s_hD[t];
            s_hD[t] = hnew;
            s_h16[t] = (_Float16)hnew;
        }
        __syncthreads();
        int w = t >> 6;
        if (w < 2) {
            int lane = t & 63;
            float pp = 0.0f;
            for (int m = lane; m < G3; m += 64) pp += s_hD[m] * fcw[w * G3 + m];
#pragma unroll
            for (int off = 32; off > 0; off >>= 1) pp += __shfl_down(pp, off);
            if (lane == 0) {
                pres += pp + fcb[w];
                out[i * 2 + w] = pres;
            }
        }
    }
}

extern "C" void kernel_launch(void* const* d_in, const int* in_sizes, int n_in,
                              void* d_out, int out_size, void* d_ws, size_t ws_size,
                              hipStream_t stream) {
    (void)in_sizes; (void)n_in; (void)out_size; (void)ws_size;
    const float* past   = (const float*)d_in[0];
    const float* future = (const float*)d_in[1];
    const float* x      = (const float*)d_in[2];
    const int*   ei     = (const int*)d_in[3];
    const float* ew     = (const float*)d_in[4];
    const float* cpw    = (const float*)d_in[5];
    const float* cpb    = (const float*)d_in[6];
    const float* cfw    = (const float*)d_in[7];
    const float* cfb    = (const float*)d_in[8];
    const float* epWih  = (const float*)d_in[9];
    const float* epWhh  = (const float*)d_in[10];
    const float* epbih  = (const float*)d_in[11];
    const float* epbhh  = (const float*)d_in[12];
    const float* efWih  = (const float*)d_in[13];
    const float* efWhh  = (const float*)d_in[14];
    const float* efbih  = (const float*)d_in[15];
    const float* efbhh  = (const float*)d_in[16];
    const float* dWih   = (const float*)d_in[17];
    const float* dWhh   = (const float*)d_in[18];
    const float* dbih   = (const float*)d_in[19];
    const float* dbhh   = (const float*)d_in[20];
    const float* fcw    = (const float*)d_in[21];
    const float* fcb    = (const float*)d_in[22];
    const float* g1w    = (const float*)d_in[23];
    const float* g1b    = (const float*)d_in[24];
    const float* g2w    = (const float*)d_in[25];
    const float* g2b    = (const float*)d_in[26];

    char* ws = (char*)d_ws;
    int*      mark1 = (int*)(ws + OFF_MARK1);
    int*      mark2 = (int*)(ws + OFF_MARK2);
    unsigned* cnt   = (unsigned*)(ws + OFF_CNT);
    unsigned* bar   = (unsigned*)(ws + OFF_BAR);
    int*      l1r   = (int*)(ws + OFF_L1R);
    float*    l1w   = (float*)(ws + OFF_L1W);
    int*      s1g   = (int*)(ws + OFF_S1G);
    int*      e2r   = (int*)(ws + OFF_E2R);
    int*      e2s   = (int*)(ws + OFF_E2S);
    float*    e2w   = (float*)(ws + OFF_E2W);
    int*      s2    = (int*)(ws + OFF_S2);
    float*    deg2  = (float*)(ws + OFF_DEG2);
    float*    state = (float*)(ws + OFF_STATE);
    float*    x1    = (float*)(ws + OFF_X1);
    float*    tpsf  = (float*)(ws + OFF_TPSF);
    float*    out   = (float*)d_out;

    hipMemsetAsync(ws, 0, OFF_L1R, stream);  // marks + cnt + barriers
    k_main<<<GRID, 256, 0, stream>>>(
        past, future, x, ei, ew,
        cpw, cpb, cfw, cfb,
        epWih, epWhh, epbih, epbhh,
        efWih, efWhh, efbih, efbhh,
        g1w, g1b,
        mark1, mark2, cnt, bar,
        l1r, l1w, s1g, e2r, e2s, e2w,
        s2, deg2, state, x1, tpsf);
    k_dec2<<<1, 448, 0, stream>>>(cnt, l1r, l1w, mark1, mark2, deg2, x1,
                                  g2w, g2b, tpsf, past,
                                  dWih, dWhh, dbih, dbhh, fcw, fcb, out);
}